// Round 5
// baseline (281.958 us; speedup 1.0000x reference)
//
#include <hip/hip_runtime.h>
#include <math.h>

// Problem constants (B=2, C=64, CI=32, T=16, H=W=14)
#define S3   3136      // per-channel spatial size = 16*196
#define PB   100352    // per-batch proj elements = 32*3136
#define XB   200704    // per-batch x elements = 64*3136
#define NN   6272      // CI*H*W = spatial attention sequence length
#define MW   7         // spatial m-split (waves per 32-n tile)
#define MPW  896       // m per wave = NN/MW
#define TGC  49        // temporal gram chunks (128 n each)

typedef __attribute__((ext_vector_type(8))) short bf16x8;   // 8 bf16 = 4 VGPRs
typedef __attribute__((ext_vector_type(16))) float f32x16;  // MFMA C/D 32x32
typedef __attribute__((ext_vector_type(4))) uint u32x4;

__device__ inline ushort f2bf(float f) {     // RNE f32 -> bf16
    uint u = __float_as_uint(f);
    return (ushort)((u + 0x7FFFu + ((u >> 16) & 1u)) >> 16);
}

__device__ inline uint cvtpk(float lo, float hi) {   // pack 2 f32 -> 2 bf16
    uint r;
    asm("v_cvt_pk_bf16_f32 %0, %1, %2" : "=v"(r) : "v"(lo), "v"(hi));
    return r;
}

__device__ inline void swap32(uint &a, uint &b) {    // a=[a_lo|b_lo], b=[a_hi|b_hi]
    asm("v_permlane32_swap_b32 %0, %1" : "+v"(a), "+v"(b));
}

// ---------------------------------------------------------------------------
// Software grid barrier (no cooperative API). 512 blocks guaranteed
// co-resident: __launch_bounds__(256,2) -> VGPR<=256 -> 2 blocks/CU x 256 CU.
// Tree: 32 groups x 16 arrivals (separate cachelines) + root. AGENT-scope
// acq/rel atomics give cross-XCD visibility (writeback on release,
// invalidate on acquire). Counters zeroed by hipMemsetAsync each launch.
// Bounded spin: a logic failure produces a wrong answer, never a hang.
// ---------------------------------------------------------------------------
__device__ inline void gridbar(uint* bar, int phase) {
    __syncthreads();                      // block's stores drained (vmcnt 0)
    if (threadIdx.x == 0) {
        uint* grp  = bar + phase * 528 + ((blockIdx.x >> 4) << 4);
        uint* root = bar + phase * 528 + 512;
        uint old = __hip_atomic_fetch_add(grp, 1u, __ATOMIC_ACQ_REL,
                                          __HIP_MEMORY_SCOPE_AGENT);
        if (old == 15u)
            __hip_atomic_fetch_add(root, 1u, __ATOMIC_ACQ_REL,
                                   __HIP_MEMORY_SCOPE_AGENT);
        long spins = 0;
        while (__hip_atomic_load(root, __ATOMIC_ACQUIRE,
                                 __HIP_MEMORY_SCOPE_AGENT) < 32u) {
            __builtin_amdgcn_s_sleep(8);
            if (++spins > 20000000L) break;
        }
    }
    __syncthreads();
}

// ---------------------------------------------------------------------------
// Fused kernel. Grid = 512 blocks x 256 threads.
// Phase 1: 6 QKV projections (300 units).            gridbar(0)
// Phase 2: spatial flash attn (686) + gram (98).     gridbar(1)
// Phase 3: merge + temporal softmax + out proj (392 units).
// Bodies are bit-identical to the round-3 verified kernels.
// ---------------------------------------------------------------------------
__global__ __launch_bounds__(256, 2) void fused_kernel(
    const float* __restrict__ x,
    const float* __restrict__ W0, const float* __restrict__ b0,
    const float* __restrict__ W1, const float* __restrict__ b1,
    const float* __restrict__ W2, const float* __restrict__ b2,
    const float* __restrict__ W3, const float* __restrict__ b3,
    const float* __restrict__ W4, const float* __restrict__ b4,
    const float* __restrict__ W5, const float* __restrict__ b5,
    const float* __restrict__ Ww, const float* __restrict__ bw,
    ushort* __restrict__ Qb, ushort* __restrict__ Kb, ushort* __restrict__ Vb,
    float* __restrict__ Qt, float* __restrict__ Kt, float* __restrict__ Vt,
    float* __restrict__ Gp, float* __restrict__ Pacc, float* __restrict__ Pl,
    uint* __restrict__ bar, float* __restrict__ out)
{
    __shared__ float shpool[4096];          // 16 KB, aliased per phase
    int bid = blockIdx.x;
    int tid = threadIdx.x;

    // ================= phase 1: projections (300 units) =================
    if (bid < 300) {
        int u  = bid;
        int bx = u % 25;
        int yq = (u / 25) % 6;
        int z  = u / 150;                 // o in [z*16, z*16+16)
        const float* Wp; const float* bp;
        switch (yq) {
            case 0:  Wp = W0; bp = b0; break;
            case 1:  Wp = W1; bp = b1; break;
            case 2:  Wp = W2; bp = b2; break;
            case 3:  Wp = W3; bp = b3; break;
            case 4:  Wp = W4; bp = b4; break;
            default: Wp = W5; bp = b5; break;
        }
        int gid = bx * 256 + tid;
        if (gid < 2 * S3) {
            int b = (gid >= S3) ? 1 : 0;
            int s = gid - b * S3;

            float xr[64];
            #pragma unroll
            for (int c = 0; c < 64; ++c) xr[c] = x[(size_t)b * XB + (size_t)c * S3 + s];

            float a[16];
            #pragma unroll
            for (int oo = 0; oo < 16; ++oo) {
                int o = z * 16 + oo;
                float acc = bp[o];
                #pragma unroll
                for (int c = 0; c < 64; ++c) acc = fmaf(Wp[o * 64 + c], xr[c], acc);
                a[oo] = acc;
            }

            if (yq < 2) {
                // bf16 transposed [n][16]: o = z*16+2k+h -> t=z*8+k, n=h*S3+s
                const float sc = (yq == 0) ? 0.36067376022224085f : 1.0f; // 0.25*log2e
                ushort* ob = (yq == 0) ? Qb : Kb;
                #pragma unroll
                for (int h = 0; h < 2; ++h) {
                    int n = h * S3 + s;
                    uint u0 = f2bf(a[0 + h] * sc)  | ((uint)f2bf(a[2 + h]  * sc) << 16);
                    uint u1 = f2bf(a[4 + h] * sc)  | ((uint)f2bf(a[6 + h]  * sc) << 16);
                    uint u2 = f2bf(a[8 + h] * sc)  | ((uint)f2bf(a[10 + h] * sc) << 16);
                    uint u3 = f2bf(a[12 + h] * sc) | ((uint)f2bf(a[14 + h] * sc) << 16);
                    *(uint4*)(ob + ((size_t)(b * NN + n) * 16 + z * 8)) = make_uint4(u0, u1, u2, u3);
                }
            } else if (yq == 2) {
                // bf16 natural [t][n]: flat j=o*S3+s -> t=o>>1, n=(o&1)*S3+s
                #pragma unroll
                for (int oo = 0; oo < 16; ++oo) {
                    int o = z * 16 + oo;
                    Vb[(size_t)(b * 16 + (o >> 1)) * NN + (o & 1) * S3 + s] = f2bf(a[oo]);
                }
            } else {
                float* op = (yq == 3) ? Qt : (yq == 4) ? Kt : Vt;
                #pragma unroll
                for (int oo = 0; oo < 16; ++oo)
                    op[(size_t)b * PB + (size_t)(z * 16 + oo) * S3 + s] = a[oo];
            }
        }
    }
    gridbar(bar, 0);

    // ================= phase 2: attention (784 units) =================
    for (int u = bid; u < 784; u += 512) {
        int xb = u % 392;
        int b  = u / 392;

        if (xb >= 343) {
            // ---- temporal Gram chunk ----
            int c = xb - 343;            // 0..48
            float* qs = shpool;
            float* ks = shpool + 2048;
            size_t base = (size_t)b * PB + (size_t)c * 2048;
            for (int i = tid; i < 512; i += 256) {
                ((float4*)qs)[i] = ((const float4*)(Qt + base))[i];
                ((float4*)ks)[i] = ((const float4*)(Kt + base))[i];
            }
            __syncthreads();
            int t = tid >> 4, s = tid & 15;
            float acc = 0.0f;
            #pragma unroll 8
            for (int n = 0; n < 128; ++n)
                acc = fmaf(qs[n * 16 + t], ks[n * 16 + s], acc);
            Gp[(size_t)(b * TGC + c) * 256 + tid] = acc;
            __syncthreads();             // LDS safe for next strided unit
        } else {
            // ---- spatial flash attention, 32x32x16 ----
            int wave = __builtin_amdgcn_readfirstlane(tid >> 6);
            int lane = tid & 63;
            int col  = lane & 31;              // n within tile / m-row / t'-row
            int h    = lane >> 5;              // half: k = h*8+e
            int gw   = xb * 4 + wave;          // 0..1371
            int ntile = gw / 7;                // 0..195
            int w     = gw - ntile * 7;        // 0..6
            int nbase = ntile * 32;
            int m0    = w * MPW;

            // Q fragment (B-operand): B[k=t=h*8+e][j=n=nbase+col]
            bf16x8 qf = *(const bf16x8*)(Qb + ((size_t)(b * NN + nbase + col) * 16 + h * 8));

            const bf16x8 vzero = {0, 0, 0, 0, 0, 0, 0, 0};
            const bf16x8 vones = {16256, 16256, 16256, 16256, 16256, 16256, 16256, 16256};
            f32x16 yacc;
            #pragma unroll
            for (int r = 0; r < 16; ++r) yacc[r] = 0.0f;
            f32x16 zero16 = yacc;

            #pragma unroll 2
            for (int it = 0; it < MPW / 32; ++it) {
                int mb = m0 + it * 32;
                // K fragment (A-operand): A[row=m=mb+col][k=t=h*8+e]
                bf16x8 kf = *(const bf16x8*)(Kb + ((size_t)(b * NN + mb + col) * 16 + h * 8));
                // V fragments (A-operand) for the two PV k-steps: A[row=t'=col][k=m]
                bf16x8 vf0 = vzero, vf1 = vzero;
                if (col < 16) {
                    const ushort* vp = Vb + ((size_t)(b * 16 + col) * NN + mb + h * 8);
                    vf0 = *(const bf16x8*)(vp);
                    vf1 = *(const bf16x8*)(vp + 16);
                } else if (col == 16) { vf0 = vones; vf1 = vones; }   // l-row

                // S^T tile: D[m-row][n-col], rows (r&3)+8*(r>>2)+4h, col = n
                f32x16 st = __builtin_amdgcn_mfma_f32_32x32x16_bf16(kf, qf, zero16, 0, 0, 0);
                float pv[16];
                #pragma unroll
                for (int r = 0; r < 16; ++r) pv[r] = __builtin_amdgcn_exp2f(st[r]);

                // pack to bf16 pairs; permlane32_swap routes rows to B k-slots
                uint X0 = cvtpk(pv[0],  pv[1]),  X1 = cvtpk(pv[2],  pv[3]);
                uint Y0 = cvtpk(pv[4],  pv[5]),  Y1 = cvtpk(pv[6],  pv[7]);
                uint X2 = cvtpk(pv[8],  pv[9]),  X3 = cvtpk(pv[10], pv[11]);
                uint Y2 = cvtpk(pv[12], pv[13]), Y3 = cvtpk(pv[14], pv[15]);
                swap32(X0, Y0); swap32(X1, Y1);
                swap32(X2, Y2); swap32(X3, Y3);
                u32x4 pb0 = {X0, X1, Y0, Y1};    // B-frag rows mb+0..15
                u32x4 pb1 = {X2, X3, Y2, Y3};    // B-frag rows mb+16..31

                yacc = __builtin_amdgcn_mfma_f32_32x32x16_bf16(
                           vf0, __builtin_bit_cast(bf16x8, pb0), yacc, 0, 0, 0);
                yacc = __builtin_amdgcn_mfma_f32_32x32x16_bf16(
                           vf1, __builtin_bit_cast(bf16x8, pb1), yacc, 0, 0, 0);
            }

            // epilogue: rows 0..15 = y[t], row 16 (h0 reg 8) = l
            #pragma unroll
            for (int r = 0; r < 8; ++r) {
                int t = (r & 3) + 8 * (r >> 2) + 4 * h;
                Pacc[((size_t)(b * 16 + t) * MW + w) * NN + nbase + col] = yacc[r];
            }
            if (h == 0)
                Pl[((size_t)b * MW + w) * NN + nbase + col] = yacc[8];
        }
    }
    gridbar(bar, 1);

    // ================= phase 3: merge + out proj (392 units) =================
    if (bid < 392) {
        int b  = bid / 196;
        int sc = bid % 196;              // s chunk: [sc*16, sc*16+16)

        float* Lsh  = shpool;            // 256
        float* AshF = shpool + 256;      // [16][17] -> 272
        float* Wsh  = shpool + 544;      // [c][ci] stride 36 -> 2304
        float* Ysh  = shpool + 2848;     // [ss][ci] stride 36 -> 576

        // --- phase A ---
        {
            float a = 0.0f;
            for (int c = 0; c < TGC; ++c)
                a += Gp[(size_t)(b * TGC + c) * 256 + tid];
            Lsh[tid] = a * 0.25f;
            for (int i = tid; i < 2048; i += 256)
                Wsh[(i >> 5) * 36 + (i & 31)] = Ww[i];
        }
        __syncthreads();
        if (tid < 16) {
            int t = tid;
            const float* Lr = &Lsh[t * 16];
            float mx = -1e30f;
            #pragma unroll
            for (int s = 0; s < 16; ++s) mx = fmaxf(mx, Lr[s]);
            float e[16]; float sm = 0.0f;
            #pragma unroll
            for (int s = 0; s < 16; ++s) { e[s] = __expf(Lr[s] - mx); sm += e[s]; }
            float inv = 1.0f / sm;
            #pragma unroll
            for (int s = 0; s < 16; ++s) AshF[s * 17 + t] = e[s] * inv;
        }
        __syncthreads();

        // --- phase B: 512 Y values, 2 per thread ---
        #pragma unroll
        for (int k = 0; k < 2; ++k) {
            int idx = tid + k * 256;      // 0..511
            int ss = idx & 15;
            int ci = idx >> 4;            // 0..31
            int s  = sc * 16 + ss;
            int t  = ci >> 1;
            int nn = (ci & 1) * S3 + s;

            float a = 0.0f, l = 0.0f;
            #pragma unroll
            for (int w = 0; w < MW; ++w) {
                a += Pacc[((size_t)(b * 16 + t) * MW + w) * NN + nn];
                l += Pl[((size_t)b * MW + w) * NN + nn];
            }
            float ys = a / l;

            int t2 = nn & 15;
            const float4* vp = (const float4*)(Vt + (size_t)b * PB + (size_t)t * NN + (nn & ~15));
            float4 v0 = vp[0], v1 = vp[1], v2 = vp[2], v3 = vp[3];
            float yt = AshF[0 * 17 + t2] * v0.x;
            yt = fmaf(AshF[1 * 17 + t2],  v0.y, yt); yt = fmaf(AshF[2 * 17 + t2],  v0.z, yt);
            yt = fmaf(AshF[3 * 17 + t2],  v0.w, yt); yt = fmaf(AshF[4 * 17 + t2],  v1.x, yt);
            yt = fmaf(AshF[5 * 17 + t2],  v1.y, yt); yt = fmaf(AshF[6 * 17 + t2],  v1.z, yt);
            yt = fmaf(AshF[7 * 17 + t2],  v1.w, yt); yt = fmaf(AshF[8 * 17 + t2],  v2.x, yt);
            yt = fmaf(AshF[9 * 17 + t2],  v2.y, yt); yt = fmaf(AshF[10 * 17 + t2], v2.z, yt);
            yt = fmaf(AshF[11 * 17 + t2], v2.w, yt); yt = fmaf(AshF[12 * 17 + t2], v3.x, yt);
            yt = fmaf(AshF[13 * 17 + t2], v3.y, yt); yt = fmaf(AshF[14 * 17 + t2], v3.z, yt);
            yt = fmaf(AshF[15 * 17 + t2], v3.w, yt);

            Ysh[ss * 36 + ci] = ys + yt;
        }
        __syncthreads();

        // --- phase C: 64c x 16ss outputs, 4 per thread ---
        int ss = tid & 15;
        int cg2 = tid >> 4;               // 0..15, c = cg2*4 + k
        int s  = sc * 16 + ss;

        float acc[4];
        #pragma unroll
        for (int k = 0; k < 4; ++k) acc[k] = bw[cg2 * 4 + k];

        #pragma unroll
        for (int cb = 0; cb < 32; cb += 4) {
            float4 y4 = *(const float4*)&Ysh[ss * 36 + cb];
            #pragma unroll
            for (int k = 0; k < 4; ++k) {
                float4 w4 = *(const float4*)&Wsh[(cg2 * 4 + k) * 36 + cb];
                acc[k] = fmaf(w4.x, y4.x, acc[k]);
                acc[k] = fmaf(w4.y, y4.y, acc[k]);
                acc[k] = fmaf(w4.z, y4.z, acc[k]);
                acc[k] = fmaf(w4.w, y4.w, acc[k]);
            }
        }

        #pragma unroll
        for (int k = 0; k < 4; ++k) {
            int c = cg2 * 4 + k;
            size_t o = (size_t)b * XB + (size_t)c * S3 + s;
            out[o] = x[o] + acc[k];
        }
    }
}

// ---------------------------------------------------------------------------
extern "C" void kernel_launch(void* const* d_in, const int* in_sizes, int n_in,
                              void* d_out, int out_size, void* d_ws, size_t ws_size,
                              hipStream_t stream)
{
    const float* x   = (const float*)d_in[0];
    const float* Wqs = (const float*)d_in[1];  const float* bqs = (const float*)d_in[2];
    const float* Wks = (const float*)d_in[3];  const float* bks = (const float*)d_in[4];
    const float* Wvs = (const float*)d_in[5];  const float* bvs = (const float*)d_in[6];
    const float* Wqt = (const float*)d_in[7];  const float* bqt = (const float*)d_in[8];
    const float* Wkt = (const float*)d_in[9];  const float* bkt = (const float*)d_in[10];
    const float* Wvt = (const float*)d_in[11]; const float* bvt = (const float*)d_in[12];
    const float* Ww  = (const float*)d_in[13]; const float* bw  = (const float*)d_in[14];

    // workspace layout (float units); total ~2.42M floats + barrier = 9.7 MB
    float* ws = (float*)d_ws;
    ushort* Qb = (ushort*)(ws);            // 200704 bf16
    ushort* Kb = (ushort*)(ws + 100352);
    ushort* Vb = (ushort*)(ws + 200704);
    float* Qt  = ws + 301056;              // 200704
    float* Kt  = ws + 501760;
    float* Vt  = ws + 702464;
    float* Gp  = ws + 903168;              // 2*49*256 = 25088
    float* Pacc = ws + 928256;             // 2*16*7*6272 = 1404928
    float* Pl   = ws + 2333184;            // 2*7*6272 = 87808
    uint*  bar  = (uint*)(ws + 2420992);   // 2 phases x 528 uints = 4224 B
    float* out  = (float*)d_out;

    hipMemsetAsync(bar, 0, 2 * 528 * sizeof(uint), stream);

    fused_kernel<<<dim3(512), dim3(256), 0, stream>>>(
        x, Wqs, bqs, Wks, bks, Wvs, bvs, Wqt, bqt, Wkt, bkt, Wvt, bvt,
        Ww, bw, Qb, Kb, Vb, Qt, Kt, Vt, Gp, Pacc, Pl, bar, out);
}

// Round 6
// 125.239 us; speedup vs baseline: 2.2514x; 2.2514x over previous
//
#include <hip/hip_runtime.h>
#include <math.h>

// Problem constants (B=2, C=64, CI=32, T=16, H=W=14)
#define S3   3136      // per-channel spatial size = 16*196
#define PB   100352    // per-batch proj elements = 32*3136
#define XB   200704    // per-batch x elements = 64*3136
#define NN   6272      // CI*H*W = spatial attention sequence length
#define MW   7         // spatial m-split (waves per 32-n tile)
#define MPW  896       // m per wave = NN/MW
#define TGC  49        // temporal gram chunks (128 n each)

typedef __attribute__((ext_vector_type(8))) short bf16x8;   // 8 bf16 = 4 VGPRs
typedef __attribute__((ext_vector_type(16))) float f32x16;  // MFMA C/D 32x32
typedef __attribute__((ext_vector_type(4))) uint u32x4;

__device__ inline ushort f2bf(float f) {     // RNE f32 -> bf16
    uint u = __float_as_uint(f);
    return (ushort)((u + 0x7FFFu + ((u >> 16) & 1u)) >> 16);
}

__device__ inline uint cvtpk(float lo, float hi) {   // pack 2 f32 -> 2 bf16
    uint r;
    asm("v_cvt_pk_bf16_f32 %0, %1, %2" : "=v"(r) : "v"(lo), "v"(hi));
    return r;
}

__device__ inline void swap32(uint &a, uint &b) {    // a=[a_lo|b_lo], b=[a_hi|b_hi]
    asm("v_permlane32_swap_b32 %0, %1" : "+v"(a), "+v"(b));
}

// ---------------------------------------------------------------------------
// Kernel 1: all 6 QKV projections, 8x o-split (4 outputs per thread) for
// latency-hiding TLP: grid (25,6,8) = 2400 blocks (~9.4/CU).
//  y=0: Qspatial -> bf16 transposed [b][n][16], pre-scaled by 0.25*log2(e)
//  y=1: Kspatial -> bf16 transposed [b][n][16]
//  y=2: Vspatial -> bf16 natural    [b][t][6272]
//  y=3..5: temporal Q/K/V -> fp32 natural flat
// ---------------------------------------------------------------------------
__global__ __launch_bounds__(256) void proj_kernel(
    const float* __restrict__ x,
    const float* __restrict__ W0, const float* __restrict__ b0,
    const float* __restrict__ W1, const float* __restrict__ b1,
    const float* __restrict__ W2, const float* __restrict__ b2,
    const float* __restrict__ W3, const float* __restrict__ b3,
    const float* __restrict__ W4, const float* __restrict__ b4,
    const float* __restrict__ W5, const float* __restrict__ b5,
    ushort* __restrict__ Qb, ushort* __restrict__ Kb, ushort* __restrict__ Vb,
    float* __restrict__ Qt, float* __restrict__ Kt, float* __restrict__ Vt)
{
    const float* Wp; const float* bp;
    switch (blockIdx.y) {
        case 0:  Wp = W0; bp = b0; break;
        case 1:  Wp = W1; bp = b1; break;
        case 2:  Wp = W2; bp = b2; break;
        case 3:  Wp = W3; bp = b3; break;
        case 4:  Wp = W4; bp = b4; break;
        default: Wp = W5; bp = b5; break;
    }
    int z = blockIdx.z;               // o in [z*4, z*4+4)

    int gid = blockIdx.x * 256 + threadIdx.x;
    if (gid >= 2 * S3) return;
    int b = (gid >= S3) ? 1 : 0;
    int s = gid - b * S3;

    float xr[64];
    #pragma unroll
    for (int c = 0; c < 64; ++c) xr[c] = x[(size_t)b * XB + (size_t)c * S3 + s];

    float a[4];
    #pragma unroll
    for (int oo = 0; oo < 4; ++oo) {
        int o = z * 4 + oo;
        float acc = bp[o];
        #pragma unroll
        for (int c = 0; c < 64; ++c) acc = fmaf(Wp[o * 64 + c], xr[c], acc);
        a[oo] = acc;
    }

    if (blockIdx.y < 2) {
        // bf16 transposed [n][16]: o = z*4 + 2k + h -> t = z*2+k, n = h*S3+s
        const float sc = (blockIdx.y == 0) ? 0.36067376022224085f : 1.0f; // 0.25*log2e
        ushort* ob = (blockIdx.y == 0) ? Qb : Kb;
        #pragma unroll
        for (int h = 0; h < 2; ++h) {
            int n = h * S3 + s;
            uint u0 = f2bf(a[0 + h] * sc) | ((uint)f2bf(a[2 + h] * sc) << 16);
            *(uint*)(ob + ((size_t)(b * NN + n) * 16 + z * 2)) = u0;
        }
    } else if (blockIdx.y == 2) {
        // bf16 natural [t][n]: o -> t = o>>1, n = (o&1)*S3+s
        #pragma unroll
        for (int oo = 0; oo < 4; ++oo) {
            int o = z * 4 + oo;
            Vb[(size_t)(b * 16 + (o >> 1)) * NN + (o & 1) * S3 + s] = f2bf(a[oo]);
        }
    } else {
        float* op = (blockIdx.y == 3) ? Qt : (blockIdx.y == 4) ? Kt : Vt;
        #pragma unroll
        for (int oo = 0; oo < 4; ++oo)
            op[(size_t)b * PB + (size_t)(z * 4 + oo) * S3 + s] = a[oo];
    }
}

// ---------------------------------------------------------------------------
// Kernel 2 (heterogeneous): blocks x<343: spatial flash attention via bf16
// 32x32x16 MFMA (K=16 = t exactly; ones-row in V gives l for free; P moves
// in-register via cvt_pk_bf16 + permlane32_swap — no LDS round trip).
// blocks x>=343: temporal Gram partials from LDS-staged chunks of 128 n.
// ---------------------------------------------------------------------------
__global__ __launch_bounds__(256) void attn_kernel(
    const ushort* __restrict__ Qb, const ushort* __restrict__ Kb,
    const ushort* __restrict__ Vb, const float* __restrict__ Qt,
    const float* __restrict__ Kt,
    float* __restrict__ Pacc, float* __restrict__ Pl, float* __restrict__ Gp)
{
    __shared__ float qs[128 * 16], ks[128 * 16];   // temporal staging

    int b = blockIdx.y;

    if (blockIdx.x >= 343) {
        // ---- temporal Gram chunk ----
        int c = blockIdx.x - 343;            // 0..48
        size_t base = (size_t)b * PB + (size_t)c * 2048;
        for (int i = threadIdx.x; i < 512; i += 256) {
            ((float4*)qs)[i] = ((const float4*)(Qt + base))[i];
            ((float4*)ks)[i] = ((const float4*)(Kt + base))[i];
        }
        __syncthreads();
        int t = threadIdx.x >> 4, s = threadIdx.x & 15;
        float acc = 0.0f;
        #pragma unroll 8
        for (int n = 0; n < 128; ++n)
            acc = fmaf(qs[n * 16 + t], ks[n * 16 + s], acc);
        Gp[(size_t)(b * TGC + c) * 256 + threadIdx.x] = acc;
        return;
    }

    // ---- spatial flash attention, 32x32x16 ----
    int wave = __builtin_amdgcn_readfirstlane((int)(threadIdx.x >> 6));
    int lane = threadIdx.x & 63;
    int col  = lane & 31;                  // n within tile / m-row / t'-row
    int h    = lane >> 5;                  // half: k = h*8+e
    int gw   = blockIdx.x * 4 + wave;      // 0..1371
    int ntile = gw / 7;                    // 0..195
    int w     = gw - ntile * 7;            // 0..6
    int nbase = ntile * 32;
    int m0    = w * MPW;

    // Q fragment (B-operand): B[k=t=h*8+e][j=n=nbase+col]
    bf16x8 qf = *(const bf16x8*)(Qb + ((size_t)(b * NN + nbase + col) * 16 + h * 8));

    const bf16x8 vzero = {0, 0, 0, 0, 0, 0, 0, 0};
    const bf16x8 vones = {16256, 16256, 16256, 16256, 16256, 16256, 16256, 16256};
    f32x16 yacc;
    #pragma unroll
    for (int r = 0; r < 16; ++r) yacc[r] = 0.0f;
    f32x16 zero16 = yacc;

    #pragma unroll 2
    for (int it = 0; it < MPW / 32; ++it) {
        int mb = m0 + it * 32;
        // K fragment (A-operand): A[row=m=mb+col][k=t=h*8+e]
        bf16x8 kf = *(const bf16x8*)(Kb + ((size_t)(b * NN + mb + col) * 16 + h * 8));
        // V fragments (A-operand) for the two PV k-steps: A[row=t'=col][k=m]
        bf16x8 vf0 = vzero, vf1 = vzero;
        if (col < 16) {
            const ushort* vp = Vb + ((size_t)(b * 16 + col) * NN + mb + h * 8);
            vf0 = *(const bf16x8*)(vp);
            vf1 = *(const bf16x8*)(vp + 16);
        } else if (col == 16) { vf0 = vones; vf1 = vones; }   // l-row

        // S^T tile: D[m-row][n-col], rows (r&3)+8*(r>>2)+4h, col = n
        f32x16 st = __builtin_amdgcn_mfma_f32_32x32x16_bf16(kf, qf, zero16, 0, 0, 0);
        float pv[16];
        #pragma unroll
        for (int r = 0; r < 16; ++r) pv[r] = __builtin_amdgcn_exp2f(st[r]);

        // pack to bf16 pairs; permlane32_swap routes rows to B-operand k-slots
        uint X0 = cvtpk(pv[0],  pv[1]),  X1 = cvtpk(pv[2],  pv[3]);
        uint Y0 = cvtpk(pv[4],  pv[5]),  Y1 = cvtpk(pv[6],  pv[7]);
        uint X2 = cvtpk(pv[8],  pv[9]),  X3 = cvtpk(pv[10], pv[11]);
        uint Y2 = cvtpk(pv[12], pv[13]), Y3 = cvtpk(pv[14], pv[15]);
        swap32(X0, Y0); swap32(X1, Y1);
        swap32(X2, Y2); swap32(X3, Y3);
        u32x4 pb0 = {X0, X1, Y0, Y1};    // B-frag rows mb+0..15
        u32x4 pb1 = {X2, X3, Y2, Y3};    // B-frag rows mb+16..31

        yacc = __builtin_amdgcn_mfma_f32_32x32x16_bf16(
                   vf0, __builtin_bit_cast(bf16x8, pb0), yacc, 0, 0, 0);
        yacc = __builtin_amdgcn_mfma_f32_32x32x16_bf16(
                   vf1, __builtin_bit_cast(bf16x8, pb1), yacc, 0, 0, 0);
    }

    // epilogue: rows 0..15 = y[t], row 16 (h0 reg 8) = l
    #pragma unroll
    for (int r = 0; r < 8; ++r) {
        int t = (r & 3) + 8 * (r >> 2) + 4 * h;
        Pacc[((size_t)(b * 16 + t) * MW + w) * NN + nbase + col] = yacc[r];
    }
    if (h == 0)
        Pl[((size_t)b * MW + w) * NN + nbase + col] = yacc[8];
}

// ---------------------------------------------------------------------------
// Kernel 3: fused merge + temporal softmax + yt + output projection + residual.
// Block = (b, 8-s chunk). Grid (392, 2) = 784 blocks (~3/CU) for TLP.
//  A: reduce Gp -> logits -> softmax -> Ash[s2][t2]; stage Ww -> Wsh[c][ci].
//  B: Ysh[ss][ci] = ys(merge of 7 partials / l) + yt.   (256 Y values, 1/thread)
//  C: out[b,c,s] = x + bw[c] + sum_ci Wsh[c][ci]*Ysh[ss][ci]  (2/thread)
// ---------------------------------------------------------------------------
__global__ __launch_bounds__(256) void merge_final(
    const float* __restrict__ Pacc, const float* __restrict__ Pl,
    const float* __restrict__ Gp, const float* __restrict__ Vt,
    const float* __restrict__ x, const float* __restrict__ Ww,
    const float* __restrict__ bw, float* __restrict__ out)
{
    __shared__ float Lsh[256];
    __shared__ float Ash[16][17];    // [s2][t2]
    __shared__ float Wsh[64 * 36];   // [c][ci], stride 36 (16B-aligned, 2-way banks)
    __shared__ float Ysh[8 * 36];    // [ss][ci], stride 36

    int b  = blockIdx.y;
    int sc = blockIdx.x;             // s chunk: [sc*8, sc*8+8)

    // --- phase A ---
    {
        float a = 0.0f;
        for (int c = 0; c < TGC; ++c)
            a += Gp[(size_t)(b * TGC + c) * 256 + threadIdx.x];
        Lsh[threadIdx.x] = a * 0.25f;
        for (int i = threadIdx.x; i < 2048; i += 256)
            Wsh[(i >> 5) * 36 + (i & 31)] = Ww[i];
    }
    __syncthreads();
    if (threadIdx.x < 16) {
        int t = threadIdx.x;
        const float* Lr = &Lsh[t * 16];
        float mx = -1e30f;
        #pragma unroll
        for (int s = 0; s < 16; ++s) mx = fmaxf(mx, Lr[s]);
        float e[16]; float sm = 0.0f;
        #pragma unroll
        for (int s = 0; s < 16; ++s) { e[s] = __expf(Lr[s] - mx); sm += e[s]; }
        float inv = 1.0f / sm;
        #pragma unroll
        for (int s = 0; s < 16; ++s) Ash[s][t] = e[s] * inv;
    }
    __syncthreads();

    // --- phase B: 256 Y values, 1 per thread ---
    {
        int idx = threadIdx.x;                // 0..255
        int ss = idx & 7;
        int ci = idx >> 3;                    // 0..31
        int s  = sc * 8 + ss;
        int t  = ci >> 1;
        int nn = (ci & 1) * S3 + s;

        float a = 0.0f, l = 0.0f;
        #pragma unroll
        for (int w = 0; w < MW; ++w) {
            a += Pacc[((size_t)(b * 16 + t) * MW + w) * NN + nn];
            l += Pl[((size_t)b * MW + w) * NN + nn];
        }
        float ys = a / l;

        int t2 = nn & 15;
        const float4* vp = (const float4*)(Vt + (size_t)b * PB + (size_t)t * NN + (nn & ~15));
        float4 v0 = vp[0], v1 = vp[1], v2 = vp[2], v3 = vp[3];
        float yt = Ash[0][t2] * v0.x;
        yt = fmaf(Ash[1][t2],  v0.y, yt); yt = fmaf(Ash[2][t2],  v0.z, yt);
        yt = fmaf(Ash[3][t2],  v0.w, yt); yt = fmaf(Ash[4][t2],  v1.x, yt);
        yt = fmaf(Ash[5][t2],  v1.y, yt); yt = fmaf(Ash[6][t2],  v1.z, yt);
        yt = fmaf(Ash[7][t2],  v1.w, yt); yt = fmaf(Ash[8][t2],  v2.x, yt);
        yt = fmaf(Ash[9][t2],  v2.y, yt); yt = fmaf(Ash[10][t2], v2.z, yt);
        yt = fmaf(Ash[11][t2], v2.w, yt); yt = fmaf(Ash[12][t2], v3.x, yt);
        yt = fmaf(Ash[13][t2], v3.y, yt); yt = fmaf(Ash[14][t2], v3.z, yt);
        yt = fmaf(Ash[15][t2], v3.w, yt);

        Ysh[ss * 36 + ci] = ys + yt;
    }
    __syncthreads();

    // --- phase C: 64c x 8ss outputs, 2 per thread ---
    int ss = threadIdx.x & 7;
    int cg = threadIdx.x >> 3;               // 0..31, c = cg*2 + k
    int s  = sc * 8 + ss;

    float acc[2];
    #pragma unroll
    for (int k = 0; k < 2; ++k) acc[k] = bw[cg * 2 + k];

    #pragma unroll
    for (int cb = 0; cb < 32; cb += 4) {
        float4 y4 = *(const float4*)&Ysh[ss * 36 + cb];
        #pragma unroll
        for (int k = 0; k < 2; ++k) {
            float4 w4 = *(const float4*)&Wsh[(cg * 2 + k) * 36 + cb];
            acc[k] = fmaf(w4.x, y4.x, acc[k]);
            acc[k] = fmaf(w4.y, y4.y, acc[k]);
            acc[k] = fmaf(w4.z, y4.z, acc[k]);
            acc[k] = fmaf(w4.w, y4.w, acc[k]);
        }
    }

    #pragma unroll
    for (int k = 0; k < 2; ++k) {
        int c = cg * 2 + k;
        size_t o = (size_t)b * XB + (size_t)c * S3 + s;
        out[o] = x[o] + acc[k];
    }
}

// ---------------------------------------------------------------------------
extern "C" void kernel_launch(void* const* d_in, const int* in_sizes, int n_in,
                              void* d_out, int out_size, void* d_ws, size_t ws_size,
                              hipStream_t stream)
{
    const float* x   = (const float*)d_in[0];
    const float* Wqs = (const float*)d_in[1];  const float* bqs = (const float*)d_in[2];
    const float* Wks = (const float*)d_in[3];  const float* bks = (const float*)d_in[4];
    const float* Wvs = (const float*)d_in[5];  const float* bvs = (const float*)d_in[6];
    const float* Wqt = (const float*)d_in[7];  const float* bqt = (const float*)d_in[8];
    const float* Wkt = (const float*)d_in[9];  const float* bkt = (const float*)d_in[10];
    const float* Wvt = (const float*)d_in[11]; const float* bvt = (const float*)d_in[12];
    const float* Ww  = (const float*)d_in[13]; const float* bw  = (const float*)d_in[14];

    // workspace layout (float units); total ~2.42M floats = 9.7 MB
    float* ws = (float*)d_ws;
    ushort* Qb = (ushort*)(ws);            // 200704 bf16
    ushort* Kb = (ushort*)(ws + 100352);
    ushort* Vb = (ushort*)(ws + 200704);
    float* Qt  = ws + 301056;              // 200704
    float* Kt  = ws + 501760;
    float* Vt  = ws + 702464;
    float* Gp  = ws + 903168;              // 2*49*256 = 25088
    float* Pacc = ws + 928256;             // 2*16*7*6272 = 1404928
    float* Pl   = ws + 2333184;            // 2*7*6272 = 87808

    proj_kernel<<<dim3(25, 6, 8), 256, 0, stream>>>(
        x, Wqs, bqs, Wks, bks, Wvs, bvs, Wqt, bqt, Wkt, bkt, Wvt, bvt,
        Qb, Kb, Vb, Qt, Kt, Vt);

    attn_kernel<<<dim3(343 + TGC, 2), 256, 0, stream>>>(
        Qb, Kb, Vb, Qt, Kt, Pacc, Pl, Gp);

    merge_final<<<dim3(392, 2), 256, 0, stream>>>(
        Pacc, Pl, Gp, Vt, x, Ww, bw, (float*)d_out);
}